// Round 1
// baseline (14180.782 us; speedup 1.0000x reference)
//
#include <hip/hip_runtime.h>
#include <cstdint>

#define B_   4
#define L_   1024
#define H_   256
#define NE_  64
#define P_   512
#define E_   65536
#define R_   4
#define DW_  100
#define DC_  20
#define DT_  20
#define DD_  20
#define REL_ 97
#define N_   256      // B*NE
#define D2_  512
#define DBI_ 276
#define DIN_ 140
#define G4_  1024     // 4*H

// workspace offsets in floats (total ~14.55M floats = 58.2 MB)
#define OFF_EMB  0u
#define OFF_PRE  573440u
#define OFF_DOCS 8962048u
#define OFF_WHP  11059200u
#define OFF_ENT  11321344u
#define OFF_M    11452416u
#define OFF_AGG  11976704u
#define OFF_HS   12107776u
#define OFF_TS   12238848u
#define OFF_HD   12369920u
#define OFF_TD   12935168u
#define OFF_HPTP 13500416u
#define OFF_BL   14024704u

__device__ __forceinline__ unsigned bf16rne(float x) {
    unsigned u = __float_as_uint(x);
    return (u + 0x7fffu + ((u >> 16) & 1u)) >> 16;
}

// ---------------------------------------------------------------- embeddings
__global__ __launch_bounds__(192) void k_embed(
    const float* __restrict__ wt, const float* __restrict__ ct,
    const float* __restrict__ nt, const int* __restrict__ widx,
    const int* __restrict__ pidx, const int* __restrict__ nidx,
    float* __restrict__ emb) {
    int row = blockIdx.x;               // b*L + l
    int t = threadIdx.x;
    if (t >= DIN_) return;
    float v;
    if (t < DW_)            v = wt[(size_t)widx[row] * DW_ + t];
    else if (t < DW_ + DC_) v = ct[pidx[row] * DC_ + (t - DW_)];
    else                    v = nt[nidx[row] * DT_ + (t - DW_ - DC_)];
    emb[(size_t)row * DIN_ + t] = v;
}

// ------------------------------------------- pack Wh (both dirs) to bf16 pairs
__global__ __launch_bounds__(256) void k_pack_wh(
    const float* __restrict__ whf, const float* __restrict__ whb,
    unsigned* __restrict__ whp) {
    int gid = blockIdx.x * 256 + threadIdx.x;   // 2*128*1024
    int dir = gid >> 17;
    int rem = gid & 131071;
    int k2 = rem >> 10, j = rem & 1023;
    const float* src = dir ? whb : whf;
    unsigned lo = bf16rne(src[(2 * k2) * G4_ + j]);
    unsigned hi = bf16rne(src[(2 * k2 + 1) * G4_ + j]);
    whp[gid] = (hi << 16) | lo;
}

// ----------------------------------------- pre-gates: emb @ Wi + b (both dirs)
__global__ __launch_bounds__(256) void k_pregates(
    const float* __restrict__ emb,
    const float* __restrict__ wif, const float* __restrict__ bf,
    const float* __restrict__ wib, const float* __restrict__ bb,
    float* __restrict__ pre) {
    int dir = blockIdx.y;
    const float* Wi   = dir ? wib : wif;
    const float* bias = dir ? bb : bf;
    int x8 = blockIdx.x * 8;            // 8 (b,l) rows per block
    __shared__ float se[8 * DIN_];
    for (int idx = threadIdx.x; idx < 8 * DIN_; idx += 256)
        se[idx] = emb[(size_t)(x8 + idx / DIN_) * DIN_ + idx % DIN_];
    __syncthreads();
    int t = threadIdx.x;
    float acc[8][4];
#pragma unroll
    for (int r = 0; r < 8; r++)
#pragma unroll
        for (int q = 0; q < 4; q++) acc[r][q] = bias[t + q * 256];
    for (int k = 0; k < DIN_; k++) {
        float w0 = Wi[k * G4_ + t];
        float w1 = Wi[k * G4_ + t + 256];
        float w2 = Wi[k * G4_ + t + 512];
        float w3 = Wi[k * G4_ + t + 768];
#pragma unroll
        for (int r = 0; r < 8; r++) {
            float e = se[r * DIN_ + k];
            acc[r][0] += e * w0; acc[r][1] += e * w1;
            acc[r][2] += e * w2; acc[r][3] += e * w3;
        }
    }
#pragma unroll
    for (int r = 0; r < 8; r++) {
        float* dst = pre + ((size_t)(dir * 4096 + x8 + r)) * G4_ + t;
        dst[0] = acc[r][0]; dst[256] = acc[r][1];
        dst[512] = acc[r][2]; dst[768] = acc[r][3];
    }
}

// ---------------------------------------------------- BiLSTM, 1 block per chain
__global__ __launch_bounds__(1024) void k_lstm(
    const float* __restrict__ pre, const unsigned* __restrict__ whp,
    float* __restrict__ docs) {
    int dir = blockIdx.x >> 2, b = blockIdx.x & 3;
    __shared__ float sh[256];
    __shared__ float sg[1024];
    int j = threadIdx.x;
    if (j < 256) sh[j] = 0.f;
    float c = 0.f;
    const unsigned* wp = whp + dir * 131072;
    const float* pb = pre + (size_t)(dir * 4 + b) * (1024 * 1024);
    __syncthreads();
    for (int t = 0; t < L_; ++t) {
        int row = dir ? (L_ - 1 - t) : t;
        float g = pb[row * G4_ + j];
#pragma unroll 8
        for (int k2 = 0; k2 < 128; ++k2) {
            unsigned w = wp[k2 * G4_ + j];
            float2 h2 = *(const float2*)(&sh[2 * k2]);
            g += h2.x * __uint_as_float(w << 16);
            g += h2.y * __uint_as_float(w & 0xffff0000u);
        }
        sg[j] = g;
        __syncthreads();
        if (j < 256) {
            float ig = sg[j], fg = sg[j + 256], gg = sg[j + 512], og = sg[j + 768];
            float si = 1.f / (1.f + expf(-ig));
            float sf = 1.f / (1.f + expf(-fg));
            float so = 1.f / (1.f + expf(-og));
            c = sf * c + si * tanhf(gg);
            float h = so * tanhf(c);
            sh[j] = h;
            docs[((size_t)(b * L_ + row)) * D2_ + dir * H_ + j] = h;
        }
        __syncthreads();
    }
}

// -------------------------------------------------- entity pooling e_map @ docs
__global__ __launch_bounds__(256) void k_pool(
    const float* __restrict__ emap, const float* __restrict__ docs,
    float* __restrict__ ent) {
    int n = blockIdx.x;                 // b*64 + e
    int b = n >> 6;
    __shared__ float sm[1024];
    for (int idx = threadIdx.x; idx < 1024; idx += 256)
        sm[idx] = emap[(size_t)n * 1024 + idx];
    __syncthreads();
    int d = threadIdx.x;
    float a0 = 0.f, a1 = 0.f;
    const float* db = docs + (size_t)b * L_ * D2_;
#pragma unroll 4
    for (int l = 0; l < L_; l++) {
        float mv = sm[l];
        a0 += mv * db[l * D2_ + d];
        a1 += mv * db[l * D2_ + d + 256];
    }
    ent[n * D2_ + d] = a0;
    ent[n * D2_ + d + 256] = a1;
}

// ------------------------------------------- per-relation messages relu(ent@W_rel)
__global__ __launch_bounds__(256) void k_msg(
    const float* __restrict__ ent, const float* __restrict__ wrel,
    float* __restrict__ m) {
    int n = blockIdx.x, r = blockIdx.y;
    __shared__ float se[512];
    for (int idx = threadIdx.x; idx < 512; idx += 256) se[idx] = ent[n * D2_ + idx];
    __syncthreads();
    int d = threadIdx.x;
    const float* W = wrel + (size_t)r * D2_ * D2_;
    float a0 = 0.f, a1 = 0.f;
#pragma unroll 4
    for (int k = 0; k < 512; k++) {
        float e = se[k];
        a0 += e * W[k * 512 + d];
        a1 += e * W[k * 512 + d + 256];
    }
    size_t o = ((size_t)(r * N_ + n)) * D2_;
    m[o + d] = fmaxf(a0, 0.f);
    m[o + d + 256] = fmaxf(a1, 0.f);
}

// --------------------------------------------------------- edge scatter-add
__global__ __launch_bounds__(256) void k_scatter(
    const int* __restrict__ esrc, const int* __restrict__ edst,
    const int* __restrict__ etyp, const float* __restrict__ m,
    float* __restrict__ agg) {
    int gid = blockIdx.x * 256 + threadIdx.x;   // E*128
    int e = gid >> 7, q = (gid & 127) << 2;
    int s = esrc[e], dn = edst[e], ty = etyp[e];
    const float4 v = *(const float4*)(m + ((size_t)(ty * N_ + s)) * D2_ + q);
    float* ap = agg + (size_t)dn * D2_ + q;
    atomicAdd(ap + 0, v.x); atomicAdd(ap + 1, v.y);
    atomicAdd(ap + 2, v.z); atomicAdd(ap + 3, v.w);
}

// ------------------------------------- hs/ts = relu(ent@Wself + agg@Wmsg + b)
__global__ __launch_bounds__(256) void k_hsts(
    const float* __restrict__ ent, const float* __restrict__ agg,
    const float* __restrict__ wsh, const float* __restrict__ wmh, const float* __restrict__ bh,
    const float* __restrict__ wst, const float* __restrict__ wmt, const float* __restrict__ bt,
    float* __restrict__ hs, float* __restrict__ ts) {
    int n = blockIdx.x, ty = blockIdx.y;
    const float* Ws = ty ? wst : wsh;
    const float* Wm = ty ? wmt : wmh;
    const float* bi = ty ? bt : bh;
    float* out = ty ? ts : hs;
    __shared__ float se[512], sa[512];
    for (int idx = threadIdx.x; idx < 512; idx += 256) {
        se[idx] = ent[n * 512 + idx];
        sa[idx] = agg[n * 512 + idx];
    }
    __syncthreads();
    int d = threadIdx.x;
    float a0 = bi[d], a1 = bi[d + 256];
#pragma unroll 2
    for (int k = 0; k < 512; k++) {
        float e = se[k], a = sa[k];
        a0 += e * Ws[k * 512 + d] + a * Wm[k * 512 + d];
        a1 += e * Ws[k * 512 + d + 256] + a * Wm[k * 512 + d + 256];
    }
    out[n * 512 + d] = fmaxf(a0, 0.f);
    out[n * 512 + d + 256] = fmaxf(a1, 0.f);
}

// --------------------- pair gather + head/tail projection + dis concat + hp*tp
__global__ __launch_bounds__(256) void k_pairs(
    const float* __restrict__ hs, const float* __restrict__ ts,
    const int* __restrict__ hts, const int* __restrict__ dht, const int* __restrict__ dth,
    const float* __restrict__ hW, const float* __restrict__ hb,
    const float* __restrict__ tW, const float* __restrict__ tb,
    const float* __restrict__ dis, float* __restrict__ hd, float* __restrict__ td,
    float* __restrict__ hptp) {
    int bp = blockIdx.x;                // b*P + p
    int b = bp >> 9;
    int hi = hts[bp * 2], ti = hts[bp * 2 + 1];
    __shared__ float sh[512], st[512];
    const float* hr = hs + ((size_t)(b * NE_ + hi)) * D2_;
    const float* tr = ts + ((size_t)(b * NE_ + ti)) * D2_;
    for (int idx = threadIdx.x; idx < 512; idx += 256) {
        sh[idx] = hr[idx];
        st[idx] = tr[idx];
    }
    __syncthreads();
    int d = threadIdx.x;
    float ah = hb[d], at = tb[d];
#pragma unroll 4
    for (int k = 0; k < 512; k++) {
        ah += sh[k] * hW[k * H_ + d];
        at += st[k] * tW[k * H_ + d];
    }
    hd[(size_t)bp * DBI_ + d] = ah;
    td[(size_t)bp * DBI_ + d] = at;
    hptp[(size_t)bp * H_ + d] = ah * at;
    if (d < DD_) {
        hd[(size_t)bp * DBI_ + H_ + d] = dis[dht[bp] * DD_ + d];
        td[(size_t)bp * DBI_ + H_ + d] = dis[dth[bp] * DD_ + d];
    }
}

// -------------------------- bilinear: bl = relu(hd_i W[i,j,k] td_j + b), fused
__global__ __launch_bounds__(256) void k_bili(
    const float* __restrict__ hd, const float* __restrict__ td,
    const float* __restrict__ W, const float* __restrict__ bb,
    float* __restrict__ bl) {
    int pt = blockIdx.x * 16;           // 16 pairs
    int ko = blockIdx.y * 32;           // 32 k's
    __shared__ float sHD[16][DBI_];
    __shared__ float sTD[DBI_][16];     // transposed for paired reads
    for (int idx = threadIdx.x; idx < 16 * DBI_; idx += 256) {
        int p = idx / DBI_, i = idx % DBI_;
        float hv = hd[(size_t)(pt + p) * DBI_ + i];
        float tv = td[(size_t)(pt + p) * DBI_ + i];
        sHD[p][i] = hv;
        sTD[i][p] = tv;
    }
    __syncthreads();
    int k = ko + (threadIdx.x & 31);
    int pr = threadIdx.x >> 5;          // 0..7 -> pairs pr, pr+8
    float acc0 = 0.f, acc1 = 0.f;
    for (int i = 0; i < DBI_; ++i) {
        float a0 = sHD[pr][i], a1 = sHD[pr + 8][i];
        const float* wp = W + (size_t)i * DBI_ * 256 + k;
        float t0 = 0.f, t1 = 0.f;
#pragma unroll 4
        for (int jj = 0; jj < DBI_; ++jj) {
            float w = wp[jj * 256];
            t0 += sTD[jj][pr] * w;
            t1 += sTD[jj][pr + 8] * w;
        }
        acc0 += a0 * t0;
        acc1 += a1 * t1;
    }
    float bk = bb[k];
    bl[(size_t)(pt + pr) * H_ + k] = fmaxf(acc0 + bk, 0.f);
    bl[(size_t)(pt + pr + 8) * H_ + k] = fmaxf(acc1 + bk, 0.f);
}

// ---------------------------------------------- logits = [bl | hp*tp] @ out_W
__global__ __launch_bounds__(128) void k_final(
    const float* __restrict__ bl, const float* __restrict__ hptp,
    const float* __restrict__ oW, const float* __restrict__ ob,
    float* __restrict__ out) {
    int bp = blockIdx.x;
    __shared__ float s[512];
    for (int idx = threadIdx.x; idx < 512; idx += 128)
        s[idx] = (idx < 256) ? bl[(size_t)bp * 256 + idx]
                             : hptp[(size_t)bp * 256 + idx - 256];
    __syncthreads();
    int r = threadIdx.x;
    if (r >= REL_) return;
    float a = ob[r];
#pragma unroll 4
    for (int d = 0; d < 512; d++) a += s[d] * oW[d * REL_ + r];
    out[(size_t)bp * REL_ + r] = a;
}

extern "C" void kernel_launch(void* const* d_in, const int* in_sizes, int n_in,
                              void* d_out, int out_size, void* d_ws, size_t ws_size,
                              hipStream_t stream) {
    const float* e_map    = (const float*)d_in[0];
    const float* word_t   = (const float*)d_in[1];
    const float* coref_t  = (const float*)d_in[2];
    const float* ner_t    = (const float*)d_in[3];
    const float* Wi_f     = (const float*)d_in[4];
    const float* Wh_f     = (const float*)d_in[5];
    const float* b_f      = (const float*)d_in[6];
    const float* Wi_b     = (const float*)d_in[7];
    const float* Wh_b     = (const float*)d_in[8];
    const float* b_b      = (const float*)d_in[9];
    const float* W_rel    = (const float*)d_in[10];
    const float* W_self_h = (const float*)d_in[11];
    const float* W_msg_h  = (const float*)d_in[12];
    const float* b_h      = (const float*)d_in[13];
    const float* W_self_t = (const float*)d_in[14];
    const float* W_msg_t  = (const float*)d_in[15];
    const float* b_t      = (const float*)d_in[16];
    const float* head_W   = (const float*)d_in[17];
    const float* head_b   = (const float*)d_in[18];
    const float* tail_W   = (const float*)d_in[19];
    const float* tail_b   = (const float*)d_in[20];
    const float* dis_t    = (const float*)d_in[21];
    const float* bili_W   = (const float*)d_in[22];
    const float* bili_b   = (const float*)d_in[23];
    const float* out_W    = (const float*)d_in[24];
    const float* out_b    = (const float*)d_in[25];
    const int* ctx_idx = (const int*)d_in[26];
    const int* pos     = (const int*)d_in[27];
    const int* ctx_ner = (const int*)d_in[28];
    const int* hts     = (const int*)d_in[29];
    const int* dht     = (const int*)d_in[30];
    const int* dth     = (const int*)d_in[31];
    const int* esrc    = (const int*)d_in[32];
    const int* edst    = (const int*)d_in[33];
    const int* etyp    = (const int*)d_in[34];

    float* ws = (float*)d_ws;
    float* emb  = ws + OFF_EMB;
    float* pre  = ws + OFF_PRE;
    float* docs = ws + OFF_DOCS;
    unsigned* whp = (unsigned*)(ws + OFF_WHP);
    float* ent  = ws + OFF_ENT;
    float* m    = ws + OFF_M;
    float* agg  = ws + OFF_AGG;
    float* hsb  = ws + OFF_HS;
    float* tsb  = ws + OFF_TS;
    float* hd   = ws + OFF_HD;
    float* td   = ws + OFF_TD;
    float* hptp = ws + OFF_HPTP;
    float* bl   = ws + OFF_BL;
    float* out  = (float*)d_out;

    hipLaunchKernelGGL(k_embed, dim3(B_ * L_), dim3(192), 0, stream,
                       word_t, coref_t, ner_t, ctx_idx, pos, ctx_ner, emb);
    hipLaunchKernelGGL(k_pack_wh, dim3(1024), dim3(256), 0, stream, Wh_f, Wh_b, whp);
    hipLaunchKernelGGL(k_pregates, dim3(512, 2), dim3(256), 0, stream,
                       emb, Wi_f, b_f, Wi_b, b_b, pre);
    hipLaunchKernelGGL(k_lstm, dim3(8), dim3(1024), 0, stream, pre, whp, docs);
    hipLaunchKernelGGL(k_pool, dim3(N_), dim3(256), 0, stream, e_map, docs, ent);
    hipLaunchKernelGGL(k_msg, dim3(N_, R_), dim3(256), 0, stream, ent, W_rel, m);
    hipMemsetAsync(agg, 0, (size_t)N_ * D2_ * sizeof(float), stream);
    hipLaunchKernelGGL(k_scatter, dim3(E_ * 128 / 256), dim3(256), 0, stream,
                       esrc, edst, etyp, m, agg);
    hipLaunchKernelGGL(k_hsts, dim3(N_, 2), dim3(256), 0, stream,
                       ent, agg, W_self_h, W_msg_h, b_h, W_self_t, W_msg_t, b_t, hsb, tsb);
    hipLaunchKernelGGL(k_pairs, dim3(B_ * P_), dim3(256), 0, stream,
                       hsb, tsb, hts, dht, dth, head_W, head_b, tail_W, tail_b,
                       dis_t, hd, td, hptp);
    hipLaunchKernelGGL(k_bili, dim3(128, 8), dim3(256), 0, stream, hd, td, bili_W, bili_b, bl);
    hipLaunchKernelGGL(k_final, dim3(B_ * P_), dim3(128), 0, stream, bl, hptp, out_W, out_b, out);
}

// Round 2
// 6454.723 us; speedup vs baseline: 2.1970x; 2.1970x over previous
//
#include <hip/hip_runtime.h>
#include <cstdint>

#define B_   4
#define L_   1024
#define H_   256
#define NE_  64
#define P_   512
#define E_   65536
#define R_   4
#define DW_  100
#define DC_  20
#define DT_  20
#define DD_  20
#define REL_ 97
#define N_   256      // B*NE
#define D2_  512
#define DBI_ 276
#define DIN_ 140
#define G4_  1024     // 4*H

// workspace offsets in floats
#define OFF_EMB  0u
#define OFF_PRE  573440u
#define OFF_DOCS 8962048u
#define OFF_WHP  11059200u
#define OFF_ENT  11321344u
#define OFF_M    11452416u
#define OFF_AGG  11976704u
#define OFF_HS   12107776u
#define OFF_TS   12238848u
#define OFF_HD   12369920u
#define OFF_TD   12935168u
#define OFF_HPTP 13500416u
#define OFF_BL   14024704u
// f16 buffers overlaid on emb/pre/docs (dead after k_pool):
//   Wb  : float-offset 0        .. 10,174,464   (276*9*16KB swizzled f16)
#define OFF_WB_F16   0u
//   hdb : 2048 x 288 f16
#define OFF_HDB_F16  10174464u
//   tdb : 2048 x 288 f16
#define OFF_TDB_F16  10469376u

typedef _Float16 h2v __attribute__((ext_vector_type(2)));
typedef _Float16 h8v __attribute__((ext_vector_type(8)));
typedef float f4v __attribute__((ext_vector_type(4)));
typedef unsigned int u4v __attribute__((ext_vector_type(4)));

union AFrag { h8v v; h2v h[4]; };
union TDreg { u4v u; h2v h[4]; };

__device__ __forceinline__ unsigned bf16rne(float x) {
    unsigned u = __float_as_uint(x);
    return (u + 0x7fffu + ((u >> 16) & 1u)) >> 16;
}
__device__ __forceinline__ unsigned short f16bits(float x) {
    return __builtin_bit_cast(unsigned short, (_Float16)x);
}

// ---------------------------------------------------------------- embeddings
__global__ __launch_bounds__(192) void k_embed(
    const float* __restrict__ wt, const float* __restrict__ ct,
    const float* __restrict__ nt, const int* __restrict__ widx,
    const int* __restrict__ pidx, const int* __restrict__ nidx,
    float* __restrict__ emb) {
    int row = blockIdx.x;               // b*L + l
    int t = threadIdx.x;
    if (t >= DIN_) return;
    float v;
    if (t < DW_)            v = wt[(size_t)widx[row] * DW_ + t];
    else if (t < DW_ + DC_) v = ct[pidx[row] * DC_ + (t - DW_)];
    else                    v = nt[nidx[row] * DT_ + (t - DW_ - DC_)];
    emb[(size_t)row * DIN_ + t] = v;
}

// ------------------------------------------- pack Wh (both dirs) to bf16 pairs
__global__ __launch_bounds__(256) void k_pack_wh(
    const float* __restrict__ whf, const float* __restrict__ whb,
    unsigned* __restrict__ whp) {
    int gid = blockIdx.x * 256 + threadIdx.x;   // 2*128*1024
    int dir = gid >> 17;
    int rem = gid & 131071;
    int k2 = rem >> 10, j = rem & 1023;
    const float* src = dir ? whb : whf;
    unsigned lo = bf16rne(src[(2 * k2) * G4_ + j]);
    unsigned hi = bf16rne(src[(2 * k2 + 1) * G4_ + j]);
    whp[gid] = (hi << 16) | lo;
}

// ----------------------------------------- pre-gates: emb @ Wi + b (both dirs)
__global__ __launch_bounds__(256) void k_pregates(
    const float* __restrict__ emb,
    const float* __restrict__ wif, const float* __restrict__ bf,
    const float* __restrict__ wib, const float* __restrict__ bb,
    float* __restrict__ pre) {
    int dir = blockIdx.y;
    const float* Wi   = dir ? wib : wif;
    const float* bias = dir ? bb : bf;
    int x8 = blockIdx.x * 8;            // 8 (b,l) rows per block
    __shared__ float se[8 * DIN_];
    for (int idx = threadIdx.x; idx < 8 * DIN_; idx += 256)
        se[idx] = emb[(size_t)(x8 + idx / DIN_) * DIN_ + idx % DIN_];
    __syncthreads();
    int t = threadIdx.x;
    float acc[8][4];
#pragma unroll
    for (int r = 0; r < 8; r++)
#pragma unroll
        for (int q = 0; q < 4; q++) acc[r][q] = bias[t + q * 256];
    for (int k = 0; k < DIN_; k++) {
        float w0 = Wi[k * G4_ + t];
        float w1 = Wi[k * G4_ + t + 256];
        float w2 = Wi[k * G4_ + t + 512];
        float w3 = Wi[k * G4_ + t + 768];
#pragma unroll
        for (int r = 0; r < 8; r++) {
            float e = se[r * DIN_ + k];
            acc[r][0] += e * w0; acc[r][1] += e * w1;
            acc[r][2] += e * w2; acc[r][3] += e * w3;
        }
    }
#pragma unroll
    for (int r = 0; r < 8; r++) {
        float* dst = pre + ((size_t)(dir * 4096 + x8 + r)) * G4_ + t;
        dst[0] = acc[r][0]; dst[256] = acc[r][1];
        dst[512] = acc[r][2]; dst[768] = acc[r][3];
    }
}

// ---------------------------------------------------- BiLSTM, 1 block per chain
__global__ __launch_bounds__(1024) void k_lstm(
    const float* __restrict__ pre, const unsigned* __restrict__ whp,
    float* __restrict__ docs) {
    int dir = blockIdx.x >> 2, b = blockIdx.x & 3;
    __shared__ float sh[256];
    __shared__ float sg[1024];
    int j = threadIdx.x;
    if (j < 256) sh[j] = 0.f;
    float c = 0.f;
    const unsigned* wp = whp + dir * 131072;
    const float* pb = pre + (size_t)(dir * 4 + b) * (1024 * 1024);
    __syncthreads();
    for (int t = 0; t < L_; ++t) {
        int row = dir ? (L_ - 1 - t) : t;
        float g = pb[row * G4_ + j];
#pragma unroll 8
        for (int k2 = 0; k2 < 128; ++k2) {
            unsigned w = wp[k2 * G4_ + j];
            float2 h2 = *(const float2*)(&sh[2 * k2]);
            g += h2.x * __uint_as_float(w << 16);
            g += h2.y * __uint_as_float(w & 0xffff0000u);
        }
        sg[j] = g;
        __syncthreads();
        if (j < 256) {
            float ig = sg[j], fg = sg[j + 256], gg = sg[j + 512], og = sg[j + 768];
            float si = 1.f / (1.f + expf(-ig));
            float sf = 1.f / (1.f + expf(-fg));
            float so = 1.f / (1.f + expf(-og));
            c = sf * c + si * tanhf(gg);
            float h = so * tanhf(c);
            sh[j] = h;
            docs[((size_t)(b * L_ + row)) * D2_ + dir * H_ + j] = h;
        }
        __syncthreads();
    }
}

// -------------------------------------------------- entity pooling e_map @ docs
__global__ __launch_bounds__(256) void k_pool(
    const float* __restrict__ emap, const float* __restrict__ docs,
    float* __restrict__ ent) {
    int n = blockIdx.x;                 // b*64 + e
    int b = n >> 6;
    __shared__ float sm[1024];
    for (int idx = threadIdx.x; idx < 1024; idx += 256)
        sm[idx] = emap[(size_t)n * 1024 + idx];
    __syncthreads();
    int d = threadIdx.x;
    float a0 = 0.f, a1 = 0.f;
    const float* db = docs + (size_t)b * L_ * D2_;
#pragma unroll 4
    for (int l = 0; l < L_; l++) {
        float mv = sm[l];
        a0 += mv * db[l * D2_ + d];
        a1 += mv * db[l * D2_ + d + 256];
    }
    ent[n * D2_ + d] = a0;
    ent[n * D2_ + d + 256] = a1;
}

// ------------------- convert bili_W fp32 [276][276][256] -> swizzled padded f16
// element order: chunk c=(i*9+jc) of 8192 halves; within: ns*512 + q*128 + n'*8 + t
// (jp = jc*32 + q*8 + t, n = ns*16 + n'); jp >= 276 -> 0
__global__ __launch_bounds__(256) void k_cvt_w(
    const float* __restrict__ W, unsigned short* __restrict__ Wb) {
    unsigned gid = blockIdx.x * 256 + threadIdx.x;   // < 20,348,928
    unsigned t = gid & 7u;
    unsigned np = (gid >> 3) & 15u;
    unsigned q = (gid >> 7) & 3u;
    unsigned ns = (gid >> 9) & 15u;
    unsigned c = gid >> 13;
    unsigned i = c / 9u, jc = c - i * 9u;
    unsigned jp = jc * 32u + q * 8u + t;
    float v = (jp < 276u) ? W[((size_t)i * 276u + jp) * 256u + ns * 16u + np] : 0.f;
    Wb[gid] = f16bits(v);
}

// ------------------------------------------- per-relation messages relu(ent@W_rel)
__global__ __launch_bounds__(256) void k_msg(
    const float* __restrict__ ent, const float* __restrict__ wrel,
    float* __restrict__ m) {
    int n = blockIdx.x, r = blockIdx.y;
    __shared__ float se[512];
    for (int idx = threadIdx.x; idx < 512; idx += 256) se[idx] = ent[n * D2_ + idx];
    __syncthreads();
    int d = threadIdx.x;
    const float* W = wrel + (size_t)r * D2_ * D2_;
    float a0 = 0.f, a1 = 0.f;
#pragma unroll 4
    for (int k = 0; k < 512; k++) {
        float e = se[k];
        a0 += e * W[k * 512 + d];
        a1 += e * W[k * 512 + d + 256];
    }
    size_t o = ((size_t)(r * N_ + n)) * D2_;
    m[o + d] = fmaxf(a0, 0.f);
    m[o + d + 256] = fmaxf(a1, 0.f);
}

// --------------------------------------------------------- edge scatter-add
__global__ __launch_bounds__(256) void k_scatter(
    const int* __restrict__ esrc, const int* __restrict__ edst,
    const int* __restrict__ etyp, const float* __restrict__ m,
    float* __restrict__ agg) {
    int gid = blockIdx.x * 256 + threadIdx.x;   // E*128
    int e = gid >> 7, q = (gid & 127) << 2;
    int s = esrc[e], dn = edst[e], ty = etyp[e];
    const float4 v = *(const float4*)(m + ((size_t)(ty * N_ + s)) * D2_ + q);
    float* ap = agg + (size_t)dn * D2_ + q;
    atomicAdd(ap + 0, v.x); atomicAdd(ap + 1, v.y);
    atomicAdd(ap + 2, v.z); atomicAdd(ap + 3, v.w);
}

// ------------------------------------- hs/ts = relu(ent@Wself + agg@Wmsg + b)
__global__ __launch_bounds__(256) void k_hsts(
    const float* __restrict__ ent, const float* __restrict__ agg,
    const float* __restrict__ wsh, const float* __restrict__ wmh, const float* __restrict__ bh,
    const float* __restrict__ wst, const float* __restrict__ wmt, const float* __restrict__ bt,
    float* __restrict__ hs, float* __restrict__ ts) {
    int n = blockIdx.x, ty = blockIdx.y;
    const float* Ws = ty ? wst : wsh;
    const float* Wm = ty ? wmt : wmh;
    const float* bi = ty ? bt : bh;
    float* out = ty ? ts : hs;
    __shared__ float se[512], sa[512];
    for (int idx = threadIdx.x; idx < 512; idx += 256) {
        se[idx] = ent[n * 512 + idx];
        sa[idx] = agg[n * 512 + idx];
    }
    __syncthreads();
    int d = threadIdx.x;
    float a0 = bi[d], a1 = bi[d + 256];
#pragma unroll 2
    for (int k = 0; k < 512; k++) {
        float e = se[k], a = sa[k];
        a0 += e * Ws[k * 512 + d] + a * Wm[k * 512 + d];
        a1 += e * Ws[k * 512 + d + 256] + a * Wm[k * 512 + d + 256];
    }
    out[n * 512 + d] = fmaxf(a0, 0.f);
    out[n * 512 + d + 256] = fmaxf(a1, 0.f);
}

// --------------------- pair gather + projections -> f16 hd/td (288-pad) + hp*tp
__global__ __launch_bounds__(256) void k_pairs(
    const float* __restrict__ hs, const float* __restrict__ ts,
    const int* __restrict__ hts, const int* __restrict__ dht, const int* __restrict__ dth,
    const float* __restrict__ hW, const float* __restrict__ hb,
    const float* __restrict__ tW, const float* __restrict__ tb,
    const float* __restrict__ dis,
    unsigned short* __restrict__ hdb, unsigned short* __restrict__ tdb,
    float* __restrict__ hptp) {
    int bp = blockIdx.x;                // b*P + p
    int b = bp >> 9;
    int hi = hts[bp * 2], ti = hts[bp * 2 + 1];
    __shared__ float sh[512], st[512];
    const float* hr = hs + ((size_t)(b * NE_ + hi)) * D2_;
    const float* tr = ts + ((size_t)(b * NE_ + ti)) * D2_;
    for (int idx = threadIdx.x; idx < 512; idx += 256) {
        sh[idx] = hr[idx];
        st[idx] = tr[idx];
    }
    __syncthreads();
    int d = threadIdx.x;
    float ah = hb[d], at = tb[d];
#pragma unroll 4
    for (int k = 0; k < 512; k++) {
        ah += sh[k] * hW[k * H_ + d];
        at += st[k] * tW[k * H_ + d];
    }
    size_t rb = (size_t)bp * 288;
    hdb[rb + d] = f16bits(ah);
    tdb[rb + d] = f16bits(at);
    hptp[(size_t)bp * H_ + d] = ah * at;
    if (d < DD_) {
        hdb[rb + 256 + d] = f16bits(dis[dht[bp] * DD_ + d]);
        tdb[rb + 256 + d] = f16bits(dis[dth[bp] * DD_ + d]);
    }
    if (d < 12) {
        hdb[rb + 276 + d] = 0;
        tdb[rb + 276 + d] = 0;
    }
}

// -------------------- bilinear as MFMA GEMM: blacc[p,k] += A(p,ij) Wb(ij,k)
// grid (16 m-tiles, 16 k-chunks), 512 threads = 8 waves.
// wave w: 16 pairs (m-base = bx*128 + w*16) x all 256 outputs (16 n-subtiles).
__global__ __launch_bounds__(512) void k_bili(
    const unsigned short* __restrict__ Wb, const unsigned short* __restrict__ hdb,
    const unsigned short* __restrict__ tdb, float* __restrict__ blacc) {
    int bx = blockIdx.x, kc = blockIdx.y;
    int i0 = kc * 17 + (kc < 4 ? kc : 4);
    int cnt = 17 + (kc < 4 ? 1 : 0);
    int steps = cnt * 9;
    int tid = threadIdx.x;
    int w = tid >> 6, lane = tid & 63, q = lane >> 4, n16 = lane & 15;

    __shared__ alignas(16) unsigned short Bs[2][8192];
    __shared__ unsigned short hds[128 * 18];

    // stage hd tile (i0..i0+17 always in-row thanks to 288 stride)
    for (int e = tid; e < 128 * 18; e += 512)
        hds[e] = hdb[(size_t)(bx * 128 + e / 18) * 288 + i0 + e % 18];

    // register-resident td fragments for this lane's pair
    int p = bx * 128 + w * 16 + n16;
    const u4v* tdsrc = (const u4v*)(tdb + (size_t)p * 288);
    TDreg td[9];
#pragma unroll
    for (int jc = 0; jc < 9; jc++) td[jc].u = tdsrc[jc * 4 + q];

    f4v acc[16];
#pragma unroll
    for (int i = 0; i < 16; i++) acc[i] = (f4v)0.f;

    // double-buffered B staging: chunks are contiguous 16KB, id = i0*9 + s
    const u4v* gsrc = (const u4v*)Wb + (size_t)(i0 * 9) * 1024 + tid * 2;
    u4v r0 = gsrc[0], r1 = gsrc[1];
    {
        u4v* bs0 = (u4v*)(&Bs[0][0]);
        bs0[tid * 2] = r0; bs0[tid * 2 + 1] = r1;
    }
    __syncthreads();

    int il = 0, jc = 0;
    for (int s = 0; s < steps; s++) {
        if (s + 1 < steps) {
            const u4v* gs = gsrc + (size_t)(s + 1) * 1024;
            r0 = gs[0]; r1 = gs[1];
        }
        unsigned short hraw = hds[(w * 16 + n16) * 18 + il];
        _Float16 hv = __builtin_bit_cast(_Float16, hraw);
        h2v hd2 = {hv, hv};
        AFrag af;
#pragma unroll
        for (int e2 = 0; e2 < 4; e2++) af.h[e2] = hd2 * td[jc].h[e2];
        const unsigned short* bsc = &Bs[s & 1][0];
#pragma unroll
        for (int ns = 0; ns < 16; ns++) {
            h8v bf = *(const h8v*)(bsc + ns * 512 + lane * 8);
            acc[ns] = __builtin_amdgcn_mfma_f32_16x16x32_f16(af.v, bf, acc[ns], 0, 0, 0);
        }
        if (s + 1 < steps) {
            u4v* bsn = (u4v*)(&Bs[(s + 1) & 1][0]);
            bsn[tid * 2] = r0; bsn[tid * 2 + 1] = r1;
        }
        __syncthreads();
        if (++jc == 9) { jc = 0; il++; }
    }

    // epilogue: C/D layout col=lane&15 (n), row=q*4+reg (m)
    float* dst = blacc + (size_t)(bx * 128 + w * 16 + q * 4) * 256 + n16;
#pragma unroll
    for (int ns = 0; ns < 16; ns++)
#pragma unroll
        for (int r = 0; r < 4; r++)
            atomicAdd(dst + (size_t)r * 256 + ns * 16, acc[ns][r]);
}

// ------------------- logits = [relu(blacc + bili_b) | hp*tp] @ out_W + out_b
__global__ __launch_bounds__(128) void k_final(
    const float* __restrict__ blacc, const float* __restrict__ bib,
    const float* __restrict__ hptp,
    const float* __restrict__ oW, const float* __restrict__ ob,
    float* __restrict__ out) {
    int bp = blockIdx.x;
    __shared__ float s[512];
    for (int idx = threadIdx.x; idx < 512; idx += 128)
        s[idx] = (idx < 256) ? fmaxf(blacc[(size_t)bp * 256 + idx] + bib[idx], 0.f)
                             : hptp[(size_t)bp * 256 + idx - 256];
    __syncthreads();
    int r = threadIdx.x;
    if (r >= REL_) return;
    float a = ob[r];
#pragma unroll 4
    for (int d = 0; d < 512; d++) a += s[d] * oW[d * REL_ + r];
    out[(size_t)bp * REL_ + r] = a;
}

extern "C" void kernel_launch(void* const* d_in, const int* in_sizes, int n_in,
                              void* d_out, int out_size, void* d_ws, size_t ws_size,
                              hipStream_t stream) {
    const float* e_map    = (const float*)d_in[0];
    const float* word_t   = (const float*)d_in[1];
    const float* coref_t  = (const float*)d_in[2];
    const float* ner_t    = (const float*)d_in[3];
    const float* Wi_f     = (const float*)d_in[4];
    const float* Wh_f     = (const float*)d_in[5];
    const float* b_f      = (const float*)d_in[6];
    const float* Wi_b     = (const float*)d_in[7];
    const float* Wh_b     = (const float*)d_in[8];
    const float* b_b      = (const float*)d_in[9];
    const float* W_rel    = (const float*)d_in[10];
    const float* W_self_h = (const float*)d_in[11];
    const float* W_msg_h  = (const float*)d_in[12];
    const float* b_h      = (const float*)d_in[13];
    const float* W_self_t = (const float*)d_in[14];
    const float* W_msg_t  = (const float*)d_in[15];
    const float* b_t      = (const float*)d_in[16];
    const float* head_W   = (const float*)d_in[17];
    const float* head_b   = (const float*)d_in[18];
    const float* tail_W   = (const float*)d_in[19];
    const float* tail_b   = (const float*)d_in[20];
    const float* dis_t    = (const float*)d_in[21];
    const float* bili_W   = (const float*)d_in[22];
    const float* bili_b   = (const float*)d_in[23];
    const float* out_W    = (const float*)d_in[24];
    const float* out_b    = (const float*)d_in[25];
    const int* ctx_idx = (const int*)d_in[26];
    const int* pos     = (const int*)d_in[27];
    const int* ctx_ner = (const int*)d_in[28];
    const int* hts     = (const int*)d_in[29];
    const int* dht     = (const int*)d_in[30];
    const int* dth     = (const int*)d_in[31];
    const int* esrc    = (const int*)d_in[32];
    const int* edst    = (const int*)d_in[33];
    const int* etyp    = (const int*)d_in[34];

    float* ws = (float*)d_ws;
    float* emb  = ws + OFF_EMB;
    float* pre  = ws + OFF_PRE;
    float* docs = ws + OFF_DOCS;
    unsigned* whp = (unsigned*)(ws + OFF_WHP);
    float* ent  = ws + OFF_ENT;
    float* m    = ws + OFF_M;
    float* agg  = ws + OFF_AGG;
    float* hsb  = ws + OFF_HS;
    float* tsb  = ws + OFF_TS;
    float* hptp = ws + OFF_HPTP;
    float* blacc = ws + OFF_BL;
    unsigned short* Wb  = (unsigned short*)(ws + OFF_WB_F16);
    unsigned short* hdb = (unsigned short*)(ws + OFF_HDB_F16);
    unsigned short* tdb = (unsigned short*)(ws + OFF_TDB_F16);
    float* out  = (float*)d_out;

    hipLaunchKernelGGL(k_embed, dim3(B_ * L_), dim3(192), 0, stream,
                       word_t, coref_t, ner_t, ctx_idx, pos, ctx_ner, emb);
    hipLaunchKernelGGL(k_pack_wh, dim3(1024), dim3(256), 0, stream, Wh_f, Wh_b, whp);
    hipLaunchKernelGGL(k_pregates, dim3(512, 2), dim3(256), 0, stream,
                       emb, Wi_f, b_f, Wi_b, b_b, pre);
    hipLaunchKernelGGL(k_lstm, dim3(8), dim3(1024), 0, stream, pre, whp, docs);
    hipLaunchKernelGGL(k_pool, dim3(N_), dim3(256), 0, stream, e_map, docs, ent);
    // Wb overlays emb/pre/docs -> must come after k_pool
    hipLaunchKernelGGL(k_cvt_w, dim3(79488), dim3(256), 0, stream, bili_W, Wb);
    hipLaunchKernelGGL(k_msg, dim3(N_, R_), dim3(256), 0, stream, ent, W_rel, m);
    hipMemsetAsync(agg, 0, (size_t)N_ * D2_ * sizeof(float), stream);
    hipLaunchKernelGGL(k_scatter, dim3(E_ * 128 / 256), dim3(256), 0, stream,
                       esrc, edst, etyp, m, agg);
    hipLaunchKernelGGL(k_hsts, dim3(N_, 2), dim3(256), 0, stream,
                       ent, agg, W_self_h, W_msg_h, b_h, W_self_t, W_msg_t, b_t, hsb, tsb);
    hipLaunchKernelGGL(k_pairs, dim3(B_ * P_), dim3(256), 0, stream,
                       hsb, tsb, hts, dht, dth, head_W, head_b, tail_W, tail_b,
                       dis_t, hdb, tdb, hptp);
    hipMemsetAsync(blacc, 0, (size_t)2048 * 256 * sizeof(float), stream);
    hipLaunchKernelGGL(k_bili, dim3(16, 16), dim3(512), 0, stream, Wb, hdb, tdb, blacc);
    hipLaunchKernelGGL(k_final, dim3(B_ * P_), dim3(128), 0, stream,
                       blacc, bili_b, hptp, out_W, out_b, out);
}

// Round 3
// 3040.096 us; speedup vs baseline: 4.6646x; 2.1232x over previous
//
#include <hip/hip_runtime.h>
#include <cstdint>

#define B_   4
#define L_   1024
#define H_   256
#define NE_  64
#define P_   512
#define E_   65536
#define R_   4
#define DW_  100
#define DC_  20
#define DT_  20
#define DD_  20
#define REL_ 97
#define N_   256      // B*NE
#define D2_  512
#define DBI_ 276
#define DIN_ 140
#define G4_  1024     // 4*H

// workspace offsets in floats
#define OFF_EMB  0u
#define OFF_PRE  573440u
#define OFF_DOCS 8962048u
#define OFF_WHP  11059200u
#define OFF_ENT  11321344u
#define OFF_M    11452416u
#define OFF_AGG  11976704u
#define OFF_HS   12107776u
#define OFF_TS   12238848u
#define OFF_HD   12369920u
#define OFF_TD   12935168u
#define OFF_HPTP 13500416u
#define OFF_BL   14024704u
// f16 buffers overlaid on emb/pre/docs (dead after k_pool):
#define OFF_WB_F16   0u
#define OFF_HDB_F16  10174464u
#define OFF_TDB_F16  10469376u

typedef _Float16 h2v __attribute__((ext_vector_type(2)));
typedef _Float16 h8v __attribute__((ext_vector_type(8)));
typedef float f4v __attribute__((ext_vector_type(4)));
typedef unsigned int u4v __attribute__((ext_vector_type(4)));

union AFrag { h8v v; h2v h[4]; };
union TDreg { u4v u; h2v h[4]; };

__device__ __forceinline__ unsigned short f16bits(float x) {
    return __builtin_bit_cast(unsigned short, (_Float16)x);
}

#if __has_builtin(__builtin_amdgcn_fdot2)
__device__ __forceinline__ float fdot2u(unsigned w, unsigned h, float acc) {
    return __builtin_amdgcn_fdot2(__builtin_bit_cast(h2v, w),
                                  __builtin_bit_cast(h2v, h), acc, false);
}
#else
__device__ __forceinline__ float fdot2u(unsigned w, unsigned h, float acc) {
    h2v wv = __builtin_bit_cast(h2v, w), hv = __builtin_bit_cast(h2v, h);
    acc = fmaf((float)wv.x, (float)hv.x, acc);
    return fmaf((float)wv.y, (float)hv.y, acc);
}
#endif

// ---------------------------------------------------------------- embeddings
__global__ __launch_bounds__(192) void k_embed(
    const float* __restrict__ wt, const float* __restrict__ ct,
    const float* __restrict__ nt, const int* __restrict__ widx,
    const int* __restrict__ pidx, const int* __restrict__ nidx,
    float* __restrict__ emb) {
    int row = blockIdx.x;               // b*L + l
    int t = threadIdx.x;
    if (t >= DIN_) return;
    float v;
    if (t < DW_)            v = wt[(size_t)widx[row] * DW_ + t];
    else if (t < DW_ + DC_) v = ct[pidx[row] * DC_ + (t - DW_)];
    else                    v = nt[nidx[row] * DT_ + (t - DW_ - DC_)];
    emb[(size_t)row * DIN_ + t] = v;
}

// -------------------------------------------- pack Wh (both dirs) to f16 pairs
__global__ __launch_bounds__(256) void k_pack_wh(
    const float* __restrict__ whf, const float* __restrict__ whb,
    unsigned* __restrict__ whp) {
    int gid = blockIdx.x * 256 + threadIdx.x;   // 2*128*1024
    int dir = gid >> 17;
    int rem = gid & 131071;
    int k2 = rem >> 10, j = rem & 1023;
    const float* src = dir ? whb : whf;
    unsigned lo = f16bits(src[(2 * k2) * G4_ + j]);
    unsigned hi = f16bits(src[(2 * k2 + 1) * G4_ + j]);
    whp[gid] = (hi << 16) | lo;
}

// ----------------------------------------- pre-gates: emb @ Wi + b (both dirs)
__global__ __launch_bounds__(256) void k_pregates(
    const float* __restrict__ emb,
    const float* __restrict__ wif, const float* __restrict__ bf,
    const float* __restrict__ wib, const float* __restrict__ bb,
    float* __restrict__ pre) {
    int dir = blockIdx.y;
    const float* Wi   = dir ? wib : wif;
    const float* bias = dir ? bb : bf;
    int x8 = blockIdx.x * 8;            // 8 (b,l) rows per block
    __shared__ float se[8 * DIN_];
    for (int idx = threadIdx.x; idx < 8 * DIN_; idx += 256)
        se[idx] = emb[(size_t)(x8 + idx / DIN_) * DIN_ + idx % DIN_];
    __syncthreads();
    int t = threadIdx.x;
    float acc[8][4];
#pragma unroll
    for (int r = 0; r < 8; r++)
#pragma unroll
        for (int q = 0; q < 4; q++) acc[r][q] = bias[t + q * 256];
    for (int k = 0; k < DIN_; k++) {
        float w0 = Wi[k * G4_ + t];
        float w1 = Wi[k * G4_ + t + 256];
        float w2 = Wi[k * G4_ + t + 512];
        float w3 = Wi[k * G4_ + t + 768];
#pragma unroll
        for (int r = 0; r < 8; r++) {
            float e = se[r * DIN_ + k];
            acc[r][0] += e * w0; acc[r][1] += e * w1;
            acc[r][2] += e * w2; acc[r][3] += e * w3;
        }
    }
#pragma unroll
    for (int r = 0; r < 8; r++) {
        float* dst = pre + ((size_t)(dir * 4096 + x8 + r)) * G4_ + t;
        dst[0] = acc[r][0]; dst[256] = acc[r][1];
        dst[512] = acc[r][2]; dst[768] = acc[r][3];
    }
}

// --------------- BiLSTM: weights VGPR+LDS resident, v_dot2_f32_f16 inner loop
// 8 blocks (dir x batch) x 512 threads; thread j owns gate columns j and j+512.
// k2 in [0,96) in regs; k2 in [96,128) in LDS (stride 68 u32: 16B-aligned rows).
__global__ __launch_bounds__(512, 2) void k_lstm(
    const float* __restrict__ pre, const unsigned* __restrict__ whp,
    float* __restrict__ docs) {
    int dir = blockIdx.x >> 2, b = blockIdx.x & 3;
    int j = threadIdx.x;
    __shared__ alignas(16) unsigned wlds[512 * 68];
    __shared__ alignas(16) unsigned sh2[128];   // h state, f16 pairs
    __shared__ float sg[1024];                  // gate exchange
    const unsigned* wp = whp + dir * 131072;
    const float* pb = pre + (size_t)(dir * 4 + b) * (1024 * 1024);

    unsigned wr0[96], wr1[96];
#pragma unroll
    for (int m = 0; m < 96; m++) {
        wr0[m] = wp[m * 1024 + j];
        wr1[m] = wp[m * 1024 + j + 512];
    }
#pragma unroll
    for (int m = 0; m < 32; m++) {
        wlds[j * 68 + m]      = wp[(96 + m) * 1024 + j];
        wlds[j * 68 + 32 + m] = wp[(96 + m) * 1024 + j + 512];
    }
    if (j < 128) sh2[j] = 0u;
    float c = 0.f;                              // live for j < 256
    __syncthreads();

    const u4v* hp  = (const u4v*)sh2;
    const u4v* w0p = (const u4v*)(wlds + j * 68);
    const u4v* w1p = (const u4v*)(wlds + j * 68 + 32);

#pragma unroll 1
    for (int t = 0; t < L_; ++t) {
        int row = dir ? (L_ - 1 - t) : t;
        float gp0 = pb[row * G4_ + j];          // issued early, used at end
        float gp1 = pb[row * G4_ + j + 512];
        float a0 = 0.f, a1 = 0.f;
#pragma unroll
        for (int m = 0; m < 24; m++) {
            u4v hv = hp[m];
#pragma unroll
            for (int e = 0; e < 4; e++) {
                a0 = fdot2u(wr0[4 * m + e], hv[e], a0);
                a1 = fdot2u(wr1[4 * m + e], hv[e], a1);
            }
        }
#pragma unroll
        for (int m = 0; m < 8; m++) {
            u4v hv = hp[24 + m];
            u4v wv0 = w0p[m];
            u4v wv1 = w1p[m];
#pragma unroll
            for (int e = 0; e < 4; e++) {
                a0 = fdot2u(wv0[e], hv[e], a0);
                a1 = fdot2u(wv1[e], hv[e], a1);
            }
        }
        sg[j] = a0 + gp0;
        sg[j + 512] = a1 + gp1;
        __syncthreads();
        if (j < 256) {
            float ig = sg[j], fg = sg[j + 256], gg = sg[j + 512], og = sg[j + 768];
            float si = 1.f / (1.f + expf(-ig));
            float sf = 1.f / (1.f + expf(-fg));
            float so = 1.f / (1.f + expf(-og));
            c = sf * c + si * tanhf(gg);
            float h = so * tanhf(c);
            ((_Float16*)sh2)[j] = (_Float16)h;  // ds_write_b16 into pair
            docs[((size_t)(b * L_ + row)) * D2_ + dir * H_ + j] = h;
        }
        __syncthreads();
    }
}

// -------------------------------------------------- entity pooling e_map @ docs
__global__ __launch_bounds__(256) void k_pool(
    const float* __restrict__ emap, const float* __restrict__ docs,
    float* __restrict__ ent) {
    int n = blockIdx.x;                 // b*64 + e
    int b = n >> 6;
    __shared__ float sm[1024];
    for (int idx = threadIdx.x; idx < 1024; idx += 256)
        sm[idx] = emap[(size_t)n * 1024 + idx];
    __syncthreads();
    int d = threadIdx.x;
    float a0 = 0.f, a1 = 0.f;
    const float* db = docs + (size_t)b * L_ * D2_;
#pragma unroll 4
    for (int l = 0; l < L_; l++) {
        float mv = sm[l];
        a0 += mv * db[l * D2_ + d];
        a1 += mv * db[l * D2_ + d + 256];
    }
    ent[n * D2_ + d] = a0;
    ent[n * D2_ + d + 256] = a1;
}

// ------------------- convert bili_W fp32 [276][276][256] -> swizzled padded f16
__global__ __launch_bounds__(256) void k_cvt_w(
    const float* __restrict__ W, unsigned short* __restrict__ Wb) {
    unsigned gid = blockIdx.x * 256 + threadIdx.x;   // < 20,348,928
    unsigned t = gid & 7u;
    unsigned np = (gid >> 3) & 15u;
    unsigned q = (gid >> 7) & 3u;
    unsigned ns = (gid >> 9) & 15u;
    unsigned c = gid >> 13;
    unsigned i = c / 9u, jc = c - i * 9u;
    unsigned jp = jc * 32u + q * 8u + t;
    float v = (jp < 276u) ? W[((size_t)i * 276u + jp) * 256u + ns * 16u + np] : 0.f;
    Wb[gid] = f16bits(v);
}

// ------------------------------------------- per-relation messages relu(ent@W_rel)
__global__ __launch_bounds__(256) void k_msg(
    const float* __restrict__ ent, const float* __restrict__ wrel,
    float* __restrict__ m) {
    int n = blockIdx.x, r = blockIdx.y;
    __shared__ float se[512];
    for (int idx = threadIdx.x; idx < 512; idx += 256) se[idx] = ent[n * D2_ + idx];
    __syncthreads();
    int d = threadIdx.x;
    const float* W = wrel + (size_t)r * D2_ * D2_;
    float a0 = 0.f, a1 = 0.f;
#pragma unroll 4
    for (int k = 0; k < 512; k++) {
        float e = se[k];
        a0 += e * W[k * 512 + d];
        a1 += e * W[k * 512 + d + 256];
    }
    size_t o = ((size_t)(r * N_ + n)) * D2_;
    m[o + d] = fmaxf(a0, 0.f);
    m[o + d + 256] = fmaxf(a1, 0.f);
}

// --------------------------------------------------------- edge scatter-add
__global__ __launch_bounds__(256) void k_scatter(
    const int* __restrict__ esrc, const int* __restrict__ edst,
    const int* __restrict__ etyp, const float* __restrict__ m,
    float* __restrict__ agg) {
    int gid = blockIdx.x * 256 + threadIdx.x;   // E*128
    int e = gid >> 7, q = (gid & 127) << 2;
    int s = esrc[e], dn = edst[e], ty = etyp[e];
    const float4 v = *(const float4*)(m + ((size_t)(ty * N_ + s)) * D2_ + q);
    float* ap = agg + (size_t)dn * D2_ + q;
    atomicAdd(ap + 0, v.x); atomicAdd(ap + 1, v.y);
    atomicAdd(ap + 2, v.z); atomicAdd(ap + 3, v.w);
}

// ------------------------------------- hs/ts = relu(ent@Wself + agg@Wmsg + b)
__global__ __launch_bounds__(256) void k_hsts(
    const float* __restrict__ ent, const float* __restrict__ agg,
    const float* __restrict__ wsh, const float* __restrict__ wmh, const float* __restrict__ bh,
    const float* __restrict__ wst, const float* __restrict__ wmt, const float* __restrict__ bt,
    float* __restrict__ hs, float* __restrict__ ts) {
    int n = blockIdx.x, ty = blockIdx.y;
    const float* Ws = ty ? wst : wsh;
    const float* Wm = ty ? wmt : wmh;
    const float* bi = ty ? bt : bh;
    float* out = ty ? ts : hs;
    __shared__ float se[512], sa[512];
    for (int idx = threadIdx.x; idx < 512; idx += 256) {
        se[idx] = ent[n * 512 + idx];
        sa[idx] = agg[n * 512 + idx];
    }
    __syncthreads();
    int d = threadIdx.x;
    float a0 = bi[d], a1 = bi[d + 256];
#pragma unroll 2
    for (int k = 0; k < 512; k++) {
        float e = se[k], a = sa[k];
        a0 += e * Ws[k * 512 + d] + a * Wm[k * 512 + d];
        a1 += e * Ws[k * 512 + d + 256] + a * Wm[k * 512 + d + 256];
    }
    out[n * 512 + d] = fmaxf(a0, 0.f);
    out[n * 512 + d + 256] = fmaxf(a1, 0.f);
}

// --------------------- pair gather + projections -> f16 hd/td (288-pad) + hp*tp
__global__ __launch_bounds__(256) void k_pairs(
    const float* __restrict__ hs, const float* __restrict__ ts,
    const int* __restrict__ hts, const int* __restrict__ dht, const int* __restrict__ dth,
    const float* __restrict__ hW, const float* __restrict__ hb,
    const float* __restrict__ tW, const float* __restrict__ tb,
    const float* __restrict__ dis,
    unsigned short* __restrict__ hdb, unsigned short* __restrict__ tdb,
    float* __restrict__ hptp) {
    int bp = blockIdx.x;                // b*P + p
    int b = bp >> 9;
    int hi = hts[bp * 2], ti = hts[bp * 2 + 1];
    __shared__ float sh[512], st[512];
    const float* hr = hs + ((size_t)(b * NE_ + hi)) * D2_;
    const float* tr = ts + ((size_t)(b * NE_ + ti)) * D2_;
    for (int idx = threadIdx.x; idx < 512; idx += 256) {
        sh[idx] = hr[idx];
        st[idx] = tr[idx];
    }
    __syncthreads();
    int d = threadIdx.x;
    float ah = hb[d], at = tb[d];
#pragma unroll 4
    for (int k = 0; k < 512; k++) {
        ah += sh[k] * hW[k * H_ + d];
        at += st[k] * tW[k * H_ + d];
    }
    size_t rb = (size_t)bp * 288;
    hdb[rb + d] = f16bits(ah);
    tdb[rb + d] = f16bits(at);
    hptp[(size_t)bp * H_ + d] = ah * at;
    if (d < DD_) {
        hdb[rb + 256 + d] = f16bits(dis[dht[bp] * DD_ + d]);
        tdb[rb + 256 + d] = f16bits(dis[dth[bp] * DD_ + d]);
    }
    if (d < 12) {
        hdb[rb + 276 + d] = 0;
        tdb[rb + 276 + d] = 0;
    }
}

// -------------------- bilinear as MFMA GEMM: blacc[p,k] += A(p,ij) Wb(ij,k)
__global__ __launch_bounds__(512) void k_bili(
    const unsigned short* __restrict__ Wb, const unsigned short* __restrict__ hdb,
    const unsigned short* __restrict__ tdb, float* __restrict__ blacc) {
    int bx = blockIdx.x, kc = blockIdx.y;
    int i0 = kc * 17 + (kc < 4 ? kc : 4);
    int cnt = 17 + (kc < 4 ? 1 : 0);
    int steps = cnt * 9;
    int tid = threadIdx.x;
    int w = tid >> 6, lane = tid & 63, q = lane >> 4, n16 = lane & 15;

    __shared__ alignas(16) unsigned short Bs[2][8192];
    __shared__ unsigned short hds[128 * 18];

    for (int e = tid; e < 128 * 18; e += 512)
        hds[e] = hdb[(size_t)(bx * 128 + e / 18) * 288 + i0 + e % 18];

    int p = bx * 128 + w * 16 + n16;
    const u4v* tdsrc = (const u4v*)(tdb + (size_t)p * 288);
    TDreg td[9];
#pragma unroll
    for (int jc = 0; jc < 9; jc++) td[jc].u = tdsrc[jc * 4 + q];

    f4v acc[16];
#pragma unroll
    for (int i = 0; i < 16; i++) acc[i] = (f4v)0.f;

    const u4v* gsrc = (const u4v*)Wb + (size_t)(i0 * 9) * 1024 + tid * 2;
    u4v r0 = gsrc[0], r1 = gsrc[1];
    {
        u4v* bs0 = (u4v*)(&Bs[0][0]);
        bs0[tid * 2] = r0; bs0[tid * 2 + 1] = r1;
    }
    __syncthreads();

    int il = 0, jc = 0;
    for (int s = 0; s < steps; s++) {
        if (s + 1 < steps) {
            const u4v* gs = gsrc + (size_t)(s + 1) * 1024;
            r0 = gs[0]; r1 = gs[1];
        }
        unsigned short hraw = hds[(w * 16 + n16) * 18 + il];
        _Float16 hv = __builtin_bit_cast(_Float16, hraw);
        h2v hd2 = {hv, hv};
        AFrag af;
#pragma unroll
        for (int e2 = 0; e2 < 4; e2++) af.h[e2] = hd2 * td[jc].h[e2];
        const unsigned short* bsc = &Bs[s & 1][0];
#pragma unroll
        for (int ns = 0; ns < 16; ns++) {
            h8v bf = *(const h8v*)(bsc + ns * 512 + lane * 8);
            acc[ns] = __builtin_amdgcn_mfma_f32_16x16x32_f16(af.v, bf, acc[ns], 0, 0, 0);
        }
        if (s + 1 < steps) {
            u4v* bsn = (u4v*)(&Bs[(s + 1) & 1][0]);
            bsn[tid * 2] = r0; bsn[tid * 2 + 1] = r1;
        }
        __syncthreads();
        if (++jc == 9) { jc = 0; il++; }
    }

    float* dst = blacc + (size_t)(bx * 128 + w * 16 + q * 4) * 256 + n16;
#pragma unroll
    for (int ns = 0; ns < 16; ns++)
#pragma unroll
        for (int r = 0; r < 4; r++)
            atomicAdd(dst + (size_t)r * 256 + ns * 16, acc[ns][r]);
}

// ------------------- logits = [relu(blacc + bili_b) | hp*tp] @ out_W + out_b
__global__ __launch_bounds__(128) void k_final(
    const float* __restrict__ blacc, const float* __restrict__ bib,
    const float* __restrict__ hptp,
    const float* __restrict__ oW, const float* __restrict__ ob,
    float* __restrict__ out) {
    int bp = blockIdx.x;
    __shared__ float s[512];
    for (int idx = threadIdx.x; idx < 512; idx += 128)
        s[idx] = (idx < 256) ? fmaxf(blacc[(size_t)bp * 256 + idx] + bib[idx], 0.f)
                             : hptp[(size_t)bp * 256 + idx - 256];
    __syncthreads();
    int r = threadIdx.x;
    if (r >= REL_) return;
    float a = ob[r];
#pragma unroll 4
    for (int d = 0; d < 512; d++) a += s[d] * oW[d * REL_ + r];
    out[(size_t)bp * REL_ + r] = a;
}

extern "C" void kernel_launch(void* const* d_in, const int* in_sizes, int n_in,
                              void* d_out, int out_size, void* d_ws, size_t ws_size,
                              hipStream_t stream) {
    const float* e_map    = (const float*)d_in[0];
    const float* word_t   = (const float*)d_in[1];
    const float* coref_t  = (const float*)d_in[2];
    const float* ner_t    = (const float*)d_in[3];
    const float* Wi_f     = (const float*)d_in[4];
    const float* Wh_f     = (const float*)d_in[5];
    const float* b_f      = (const float*)d_in[6];
    const float* Wi_b     = (const float*)d_in[7];
    const float* Wh_b     = (const float*)d_in[8];
    const float* b_b      = (const float*)d_in[9];
    const float* W_rel    = (const float*)d_in[10];
    const float* W_self_h = (const float*)d_in[11];
    const float* W_msg_h  = (const float*)d_in[12];
    const float* b_h      = (const float*)d_in[13];
    const float* W_self_t = (const float*)d_in[14];
    const float* W_msg_t  = (const float*)d_in[15];
    const float* b_t      = (const float*)d_in[16];
    const float* head_W   = (const float*)d_in[17];
    const float* head_b   = (const float*)d_in[18];
    const float* tail_W   = (const float*)d_in[19];
    const float* tail_b   = (const float*)d_in[20];
    const float* dis_t    = (const float*)d_in[21];
    const float* bili_W   = (const float*)d_in[22];
    const float* bili_b   = (const float*)d_in[23];
    const float* out_W    = (const float*)d_in[24];
    const float* out_b    = (const float*)d_in[25];
    const int* ctx_idx = (const int*)d_in[26];
    const int* pos     = (const int*)d_in[27];
    const int* ctx_ner = (const int*)d_in[28];
    const int* hts     = (const int*)d_in[29];
    const int* dht     = (const int*)d_in[30];
    const int* dth     = (const int*)d_in[31];
    const int* esrc    = (const int*)d_in[32];
    const int* edst    = (const int*)d_in[33];
    const int* etyp    = (const int*)d_in[34];

    float* ws = (float*)d_ws;
    float* emb  = ws + OFF_EMB;
    float* pre  = ws + OFF_PRE;
    float* docs = ws + OFF_DOCS;
    unsigned* whp = (unsigned*)(ws + OFF_WHP);
    float* ent  = ws + OFF_ENT;
    float* m    = ws + OFF_M;
    float* agg  = ws + OFF_AGG;
    float* hsb  = ws + OFF_HS;
    float* tsb  = ws + OFF_TS;
    float* hptp = ws + OFF_HPTP;
    float* blacc = ws + OFF_BL;
    unsigned short* Wb  = (unsigned short*)(ws + OFF_WB_F16);
    unsigned short* hdb = (unsigned short*)(ws + OFF_HDB_F16);
    unsigned short* tdb = (unsigned short*)(ws + OFF_TDB_F16);
    float* out  = (float*)d_out;

    hipLaunchKernelGGL(k_embed, dim3(B_ * L_), dim3(192), 0, stream,
                       word_t, coref_t, ner_t, ctx_idx, pos, ctx_ner, emb);
    hipLaunchKernelGGL(k_pack_wh, dim3(1024), dim3(256), 0, stream, Wh_f, Wh_b, whp);
    hipLaunchKernelGGL(k_pregates, dim3(512, 2), dim3(256), 0, stream,
                       emb, Wi_f, b_f, Wi_b, b_b, pre);
    hipLaunchKernelGGL(k_lstm, dim3(8), dim3(512), 0, stream, pre, whp, docs);
    hipLaunchKernelGGL(k_pool, dim3(N_), dim3(256), 0, stream, e_map, docs, ent);
    // Wb overlays emb/pre/docs -> must come after k_pool
    hipLaunchKernelGGL(k_cvt_w, dim3(79488), dim3(256), 0, stream, bili_W, Wb);
    hipLaunchKernelGGL(k_msg, dim3(N_, R_), dim3(256), 0, stream, ent, W_rel, m);
    hipMemsetAsync(agg, 0, (size_t)N_ * D2_ * sizeof(float), stream);
    hipLaunchKernelGGL(k_scatter, dim3(E_ * 128 / 256), dim3(256), 0, stream,
                       esrc, edst, etyp, m, agg);
    hipLaunchKernelGGL(k_hsts, dim3(N_, 2), dim3(256), 0, stream,
                       ent, agg, W_self_h, W_msg_h, b_h, W_self_t, W_msg_t, b_t, hsb, tsb);
    hipLaunchKernelGGL(k_pairs, dim3(B_ * P_), dim3(256), 0, stream,
                       hsb, tsb, hts, dht, dth, head_W, head_b, tail_W, tail_b,
                       dis_t, hdb, tdb, hptp);
    hipMemsetAsync(blacc, 0, (size_t)2048 * 256 * sizeof(float), stream);
    hipLaunchKernelGGL(k_bili, dim3(16, 16), dim3(512), 0, stream, Wb, hdb, tdb, blacc);
    hipLaunchKernelGGL(k_final, dim3(B_ * P_), dim3(128), 0, stream,
                       blacc, bili_b, hptp, out_W, out_b, out);
}